// Round 5
// baseline (184.388 us; speedup 1.0000x reference)
//
#include <hip/hip_runtime.h>
#include <math.h>

#define TT 2048
#define DD 1024
#define NH 16
#define DHD 64
#define DFF 4096

typedef __attribute__((ext_vector_type(8))) short short8;
typedef __attribute__((ext_vector_type(4))) float f32x4;

#define MFMA16(a, b, c) __builtin_amdgcn_mfma_f32_16x16x32_bf16(a, b, c, 0, 0, 0)
#define GLDS16(gp, lp) __builtin_amdgcn_global_load_lds( \
    (const __attribute__((address_space(1))) void*)(gp), \
    (__attribute__((address_space(3))) void*)(lp), 16, 0, 0)

static __device__ __forceinline__ unsigned short f2b(float f) {
  unsigned u = __builtin_bit_cast(unsigned, f);
  u = u + 0x7fffu + ((u >> 16) & 1u);
  return (unsigned short)(u >> 16);
}
static __device__ __forceinline__ float b2f(unsigned short b) {
  return __builtin_bit_cast(float, (unsigned)b << 16);
}

// ---------------- fp32 -> bf16 convert: all 4 weight mats, one launch -------
__global__ __launch_bounds__(256) void f2b4_kernel(const float* __restrict__ s0,
    const float* __restrict__ s1, const float* __restrict__ s2,
    const float* __restrict__ s3, unsigned short* __restrict__ out) {
  int i = blockIdx.x * 256 + threadIdx.x;
  const float* s; int off;
  if (i < 786432)       { s = s0; off = 0; }
  else if (i < 1048576) { s = s1; off = 786432; }
  else if (i < 2097152) { s = s2; off = 1048576; }
  else                  { s = s3; off = 2097152; }
  float4 v = ((const float4*)s)[i - off];
  ushort4 o;
  o.x = f2b(v.x); o.y = f2b(v.y); o.z = f2b(v.z); o.w = f2b(v.w);
  ((ushort4*)out)[i] = o;
}

// ---------------- LayerNorm (fp32 in, bf16 out) ----------------
__global__ __launch_bounds__(256) void ln_kernel(const float* __restrict__ x,
    const float* __restrict__ w, const float* __restrict__ b,
    unsigned short* __restrict__ out) {
  int row = blockIdx.x;
  const float4* xr = (const float4*)(x + (size_t)row * DD);
  float4 v = xr[threadIdx.x];
  float s  = v.x + v.y + v.z + v.w;
  float ss = v.x * v.x + v.y * v.y + v.z * v.z + v.w * v.w;
  for (int o = 32; o > 0; o >>= 1) {
    s  += __shfl_down(s, o);
    ss += __shfl_down(ss, o);
  }
  __shared__ float red[10];
  int lane = threadIdx.x & 63, wv = threadIdx.x >> 6;
  if (lane == 0) { red[wv] = s; red[4 + wv] = ss; }
  __syncthreads();
  if (threadIdx.x == 0) {
    float S  = red[0] + red[1] + red[2] + red[3];
    float SS = red[4] + red[5] + red[6] + red[7];
    float mu  = S * (1.0f / DD);
    float var = SS * (1.0f / DD) - mu * mu;
    red[8] = mu;
    red[9] = rsqrtf(var + 1e-5f);
  }
  __syncthreads();
  float mu = red[8], inv = red[9];
  float4 wv4 = ((const float4*)w)[threadIdx.x];
  float4 bv4 = ((const float4*)b)[threadIdx.x];
  ushort4 o4;
  o4.x = f2b((v.x - mu) * inv * wv4.x + bv4.x);
  o4.y = f2b((v.y - mu) * inv * wv4.y + bv4.y);
  o4.z = f2b((v.z - mu) * inv * wv4.z + bv4.z);
  o4.w = f2b((v.w - mu) * inv * wv4.w + bv4.w);
  ((ushort4*)(out + (size_t)row * DD))[threadIdx.x] = o4;
}

// ---------------- bf16 MFMA GEMM v3: quad-buffered, counted vmcnt, BK=32 ----
// C[M,N] = A[M,K] * B[N,K]^T (+bias/gelu/resid) or bf16 partial (split-K).
// 128x128 tile, 256 threads (4 waves 2x2). LDS: 4 bufs x (A 8KB | B 8KB).
// Per wave per tile: 4 global_load_lds (2 A + 2 B) -> vmcnt counts are exact.
// LDS layout: 2 matrix rows (64B each) per 128B LDS row, XOR-swizzled by
// (ldsrow&7)<<4; stage uses inverse-swizzled global source (rule #21).
template<int FUSE_GELU, int OUT_BF16, int HAS_RESID, int PARTIAL>
__global__ __launch_bounds__(256) void gemm3(
    const unsigned short* __restrict__ A,   // [M,K] bf16
    const unsigned short* __restrict__ Bw,  // [N,K] bf16
    const float* __restrict__ bias,         // [N]
    const float* __restrict__ resid,        // [M,N] fp32
    void* __restrict__ Cout,
    int M, int N, int K, int KS) {
  __shared__ char lds[65536];
  const int tid = threadIdx.x;
  const int w = tid >> 6, l = tid & 63;
  const int l15 = l & 15, lhi = l >> 4;
  const int row0 = blockIdx.y * 128, col0 = blockIdx.x * 128;
  const int kbeg = blockIdx.z * KS;
  const int wm = (w >> 1) * 64, wn = (w & 1) * 64;

  f32x4 acc[4][4] = {};

  // staging source (inverse-swizzled): lane i -> matrix row/col for LDS slot i*16
  const int slotp = (l & 7) ^ (l >> 3);
  const int srow = w * 32 + 2 * (l >> 3) + (slotp >> 2);
  const int scolb = (slotp & 3) * 16;
  const char* aS = (const char*)A + ((size_t)(row0 + srow) * K + kbeg) * 2 + scolb;
  const char* bS = (const char*)Bw + ((size_t)(col0 + srow) * K + kbeg) * 2 + scolb;
  const size_t r16 = (size_t)K * 32;      // 16 matrix rows in bytes
  const int aLo = w * 2048;               // wave's LDS chunk in A region
  const int bLo = 8192 + w * 2048;

  // fragment read offsets within a buffer (A at +0, B at +8192)
  int aOff[4], bOff[4];
#pragma unroll
  for (int i = 0; i < 4; ++i) {
    int ra = wm + i * 16 + l15;
    aOff[i] = (ra >> 1) * 128 + (((( ra & 1) << 6) | (lhi << 4)) ^ (((ra >> 1) & 7) << 4));
    int rb = wn + i * 16 + l15;
    bOff[i] = 8192 + (rb >> 1) * 128 + ((((rb & 1) << 6) | (lhi << 4)) ^ (((rb >> 1) & 7) << 4));
  }

  const int NT = KS >> 5;   // BK = 32

  auto STAGE = [&](int t) {
    char* base = lds + (t & 3) * 16384;
    const char* a = aS + (size_t)t * 64;
    const char* b = bS + (size_t)t * 64;
    GLDS16(a, base + aLo);
    GLDS16(a + r16, base + aLo + 1024);
    GLDS16(b, base + bLo);
    GLDS16(b + r16, base + bLo + 1024);
  };
  auto COMPUTE = [&](int t) {
    const char* buf = lds + (t & 3) * 16384;
    short8 af[4], bf[4];
#pragma unroll
    for (int mi = 0; mi < 4; ++mi) af[mi] = *(const short8*)(buf + aOff[mi]);
#pragma unroll
    for (int ni = 0; ni < 4; ++ni) bf[ni] = *(const short8*)(buf + bOff[ni]);
#pragma unroll
    for (int mi = 0; mi < 4; ++mi)
#pragma unroll
      for (int ni = 0; ni < 4; ++ni)
        acc[mi][ni] = MFMA16(af[mi], bf[ni], acc[mi][ni]);
  };

  // prologue: 3 tiles in flight (12 loads/wave)
  STAGE(0); STAGE(1); STAGE(2);

  int t = 0;
  for (; t < NT - 2; ++t) {
    __builtin_amdgcn_sched_barrier(0);
    asm volatile("s_waitcnt vmcnt(8)" ::: "memory");   // tile t complete
    __builtin_amdgcn_s_barrier();
    __builtin_amdgcn_sched_barrier(0);
    if (t + 3 < NT) STAGE(t + 3);                      // overwrites buf[(t-1)&3]
    COMPUTE(t);
  }
  __builtin_amdgcn_sched_barrier(0);
  asm volatile("s_waitcnt vmcnt(4)" ::: "memory");
  __builtin_amdgcn_s_barrier();
  __builtin_amdgcn_sched_barrier(0);
  COMPUTE(NT - 2);
  __builtin_amdgcn_sched_barrier(0);
  asm volatile("s_waitcnt vmcnt(0)" ::: "memory");
  __builtin_amdgcn_s_barrier();
  __builtin_amdgcn_sched_barrier(0);
  COMPUTE(NT - 1);

  if (PARTIAL) {   // bf16 partials, no bias
    unsigned short* Cp = (unsigned short*)Cout + (size_t)blockIdx.z * M * N;
#pragma unroll
    for (int mi = 0; mi < 4; ++mi)
#pragma unroll
      for (int r = 0; r < 4; ++r) {
        size_t row = (size_t)(row0 + wm + mi * 16 + lhi * 4 + r);
#pragma unroll
        for (int ni = 0; ni < 4; ++ni)
          Cp[row * N + col0 + wn + ni * 16 + l15] = f2b(acc[mi][ni][r]);
      }
    return;
  }

#pragma unroll
  for (int mi = 0; mi < 4; ++mi) {
#pragma unroll
    for (int r = 0; r < 4; ++r) {
      size_t row = (size_t)(row0 + wm + mi * 16 + lhi * 4 + r);
#pragma unroll
      for (int ni = 0; ni < 4; ++ni) {
        int col = col0 + wn + ni * 16 + l15;
        float v = acc[mi][ni][r] + bias[col];
        if (FUSE_GELU) {
          float u = v;
          v = 0.5f * u * (1.0f + tanhf(0.7978845608028654f * (u + 0.044715f * u * u * u)));
        }
        if (HAS_RESID) v += resid[row * N + col];
        if (OUT_BF16) ((unsigned short*)Cout)[row * N + col] = f2b(v);
        else          ((float*)Cout)[row * N + col] = v;
      }
    }
  }
}

// ---------------- split-K reduce: out = sum(bf16 partials) + bias + resid ---
template<int NP>
__global__ __launch_bounds__(256) void reduce_k(const unsigned short* __restrict__ p,
    const float* __restrict__ bias, const float* __restrict__ resid,
    float* __restrict__ out) {
  int i = blockIdx.x * 256 + threadIdx.x;      // over T*D/4
  float4 r = ((const float4*)resid)[i];
  float4 bb = ((const float4*)bias)[i & (DD / 4 - 1)];
  float o0 = r.x + bb.x, o1 = r.y + bb.y, o2 = r.z + bb.z, o3 = r.w + bb.w;
#pragma unroll
  for (int z = 0; z < NP; ++z) {
    ushort4 pv = ((const ushort4*)(p + (size_t)z * TT * DD))[i];
    o0 += b2f(pv.x); o1 += b2f(pv.y); o2 += b2f(pv.z); o3 += b2f(pv.w);
  }
  float4 o; o.x = o0; o.y = o1; o.z = o2; o.w = o3;
  ((float4*)out)[i] = o;
}

// ---------------- gather heads: kqv[T,3D] bf16 -> K/Q [H,T,DH] bf16 ---------
__global__ __launch_bounds__(256) void gather_qkv(const unsigned short* __restrict__ kqv,
    unsigned short* __restrict__ Q, unsigned short* __restrict__ K) {
  int idx = blockIdx.x * 256 + threadIdx.x;   // over H*T*DH
  int d = idx & 63;
  int t = (idx >> 6) & (TT - 1);
  int h = idx >> 17;
  int col = d * NH + h;
  const unsigned short* rowp = kqv + (size_t)t * (3 * DD);
  K[idx] = rowp[col];
  Q[idx] = f2b(b2f(rowp[DD + col]) * 8.0f);   // * sqrt(DH), exact in bf16
}

// ---------------- V transpose: kqv v-section -> Vt[H][DH][T] ----------------
__global__ __launch_bounds__(256) void transpose_v(const unsigned short* __restrict__ kqv,
    unsigned short* __restrict__ Vt) {
  const int h = blockIdx.y;
  const int t0 = blockIdx.x * 64;
  __shared__ unsigned short Vs[64][65];
  for (int idx = threadIdx.x; idx < 4096; idx += 256) {
    int t = idx >> 6, d = idx & 63;
    Vs[t][d] = kqv[(size_t)(t0 + t) * (3 * DD) + 2 * DD + d * NH + h];
  }
  __syncthreads();
  for (int idx = threadIdx.x; idx < 4096; idx += 256) {
    int d = idx >> 6, t = idx & 63;
    Vt[(size_t)(h * DHD + d) * TT + t0 + t] = Vs[t][d];
  }
}

// ---------------- MFMA flash attention (as round 4) -------------------------
__global__ __launch_bounds__(256) void attn_mfma(
    const unsigned short* __restrict__ Q,   // [H,T,DH] bf16, pre-scaled
    const unsigned short* __restrict__ K,   // [H,T,DH]
    const unsigned short* __restrict__ Vt,  // [H,DH,T]
    unsigned short* __restrict__ hv) {      // [T,D] bf16, head-slow cols
  const int h = blockIdx.y;
  const int qb = gridDim.x - 1 - blockIdx.x;   // heavy blocks first
  const int q0 = qb * 64;
  const int tid = threadIdx.x;
  const int w = tid >> 6, l = tid & 63;
  const int l15 = l & 15, lhi = l >> 4;

  __shared__ char lds[40960];   // 2 x (K 8KB | V 8KB) + Ps 8KB (per-wave 2KB)
  char* Ps = lds + 32768 + w * 2048;

  const char* KhB = (const char*)(K + (size_t)h * TT * DHD);
  const char* VhB = (const char*)(Vt + (size_t)h * DHD * TT);

  const unsigned short* Qbase = Q + ((size_t)h * TT + q0 + w * 16 + l15) * DHD;
  short8 qf0 = *(const short8*)(Qbase + lhi * 8);
  short8 qf1 = *(const short8*)(Qbase + 32 + lhi * 8);

  f32x4 oacc[4] = {};
  float m = -1e30f, lsum = 0.0f;

  const int lrow = l >> 3;
  const int colb = ((l & 7) * 16) ^ (lrow << 4);
  const int srow = w * 16 + lrow;
  const int swz = (l15 & 7) << 4;

  auto stage = [&](int k0n, char* buf) {
    const char* ks = KhB + (size_t)(k0n + srow) * 128 + colb;
    GLDS16(ks, buf + w * 2048);
    GLDS16(ks + 8 * 128, buf + w * 2048 + 1024);
    const char* vs = VhB + (size_t)srow * (TT * 2) + (size_t)k0n * 2 + colb;
    GLDS16(vs, buf + 8192 + w * 2048);
    GLDS16(vs + 8 * (TT * 2), buf + 8192 + w * 2048 + 1024);
  };

  stage(0, lds);
  __syncthreads();
  int cur = 0;

  for (int kt = 0; kt <= qb; ++kt) {
    if (kt < qb) stage((kt + 1) * 64, lds + (cur ^ 1) * 16384);

    const char* Kb = lds + cur * 16384;
    const char* Vb = Kb + 8192;

    f32x4 sacc[4] = {};
    __builtin_amdgcn_s_setprio(1);
#pragma unroll
    for (int nt = 0; nt < 4; ++nt) {
      const char* rp = Kb + (nt * 16 + l15) * 128;
      short8 kb0 = *(const short8*)(rp + ((lhi * 16) ^ swz));
      short8 kb1 = *(const short8*)(rp + ((64 + lhi * 16) ^ swz));
      sacc[nt] = MFMA16(kb0, qf0, sacc[nt]);
      sacc[nt] = MFMA16(kb1, qf1, sacc[nt]);
    }
    __builtin_amdgcn_s_setprio(0);

    if (kt == qb) {
      const int qloc = w * 16 + l15;
#pragma unroll
      for (int nt = 0; nt < 4; ++nt)
#pragma unroll
        for (int r = 0; r < 4; ++r)
          if (nt * 16 + lhi * 4 + r > qloc) sacc[nt][r] = -1e30f;
    }

    float tmax = -1e30f;
#pragma unroll
    for (int nt = 0; nt < 4; ++nt)
#pragma unroll
      for (int r = 0; r < 4; ++r) tmax = fmaxf(tmax, sacc[nt][r]);
    tmax = fmaxf(tmax, __shfl_xor(tmax, 16));
    tmax = fmaxf(tmax, __shfl_xor(tmax, 32));
    float mnew = fmaxf(m, tmax);
    float al = __expf(m - mnew);
    m = mnew;
    float ssum = 0.0f;
#pragma unroll
    for (int nt = 0; nt < 4; ++nt)
#pragma unroll
      for (int r = 0; r < 4; ++r) {
        float p = __expf(sacc[nt][r] - mnew);
        sacc[nt][r] = p;
        ssum += p;
      }
    ssum += __shfl_xor(ssum, 16);
    ssum += __shfl_xor(ssum, 32);
    lsum = lsum * al + ssum;

    {
      char* pp = Ps + l15 * 128;
#pragma unroll
      for (int nt = 0; nt < 4; ++nt) {
        uint2 pk;
        pk.x = (unsigned)f2b(sacc[nt][0]) | ((unsigned)f2b(sacc[nt][1]) << 16);
        pk.y = (unsigned)f2b(sacc[nt][2]) | ((unsigned)f2b(sacc[nt][3]) << 16);
        *(uint2*)(pp + (((nt * 16 + lhi * 4) * 2) ^ swz)) = pk;
      }
    }

    float alr[4];
#pragma unroll
    for (int r = 0; r < 4; ++r) alr[r] = __shfl(al, (l & 48) | (lhi * 4 + r));
#pragma unroll
    for (int dt = 0; dt < 4; ++dt)
#pragma unroll
      for (int r = 0; r < 4; ++r) oacc[dt][r] *= alr[r];

    const char* pr = Ps + l15 * 128;
    short8 pa0 = *(const short8*)(pr + ((lhi * 16) ^ swz));
    short8 pa1 = *(const short8*)(pr + ((64 + lhi * 16) ^ swz));
    __builtin_amdgcn_s_setprio(1);
#pragma unroll
    for (int dt = 0; dt < 4; ++dt) {
      const char* vr = Vb + (dt * 16 + l15) * 128;
      short8 vb0 = *(const short8*)(vr + ((lhi * 16) ^ swz));
      short8 vb1 = *(const short8*)(vr + ((64 + lhi * 16) ^ swz));
      oacc[dt] = MFMA16(pa0, vb0, oacc[dt]);
      oacc[dt] = MFMA16(pa1, vb1, oacc[dt]);
    }
    __builtin_amdgcn_s_setprio(0);

    __syncthreads();
    cur ^= 1;
  }

  float lr[4];
#pragma unroll
  for (int r = 0; r < 4; ++r)
    lr[r] = 1.0f / __shfl(lsum, (l & 48) | (lhi * 4 + r));
#pragma unroll
  for (int r = 0; r < 4; ++r) {
    size_t orow = (size_t)(q0 + w * 16 + lhi * 4 + r) * DD + h * 64;
#pragma unroll
    for (int dt = 0; dt < 4; ++dt)
      hv[orow + dt * 16 + l15] = f2b(oacc[dt][r] * lr[r]);
  }
}

// ---------------- launch ----------------
extern "C" void kernel_launch(void* const* d_in, const int* in_sizes, int n_in,
                              void* d_out, int out_size, void* d_ws, size_t ws_size,
                              hipStream_t stream) {
  const float* x     = (const float*)d_in[0];
  const float* w_kqv = (const float*)d_in[1];
  const float* b_kqv = (const float*)d_in[2];
  const float* w_o   = (const float*)d_in[3];
  const float* b_o   = (const float*)d_in[4];
  const float* ln1_w = (const float*)d_in[5];
  const float* ln1_b = (const float*)d_in[6];
  const float* ln2_w = (const float*)d_in[7];
  const float* ln2_b = (const float*)d_in[8];
  const float* w_up  = (const float*)d_in[9];
  const float* b_up  = (const float*)d_in[10];
  const float* w_dn  = (const float*)d_in[11];
  const float* b_dn  = (const float*)d_in[12];
  float* out = (float*)d_out;

  char* W = (char*)d_ws;
  unsigned short* wkqv_b = (unsigned short*)(W);                 // [0,6) MiB
  unsigned short* wo_b   = (unsigned short*)(W + 6291456);       // [6,8)
  unsigned short* wup_b  = (unsigned short*)(W + 8388608);       // [8,16)
  unsigned short* wdn_b  = (unsigned short*)(W + 16777216);      // [16,24)
  unsigned short* h_b    = (unsigned short*)(W + 25165824);      // [24,28)
  unsigned short* kqz    = (unsigned short*)(W + 29360128);      // [28,44) kqv then z1
  unsigned short* Qg     = (unsigned short*)(W + 46137344);      // [44,48)
  unsigned short* Kg     = (unsigned short*)(W + 50331648);      // [48,52)
  unsigned short* Vtg    = (unsigned short*)(W + 54525952);      // [52,56)
  unsigned short* hv_b   = (unsigned short*)(W + 58720256);      // [56,60)
  float*          x2     = (float*)(W + 62914560);               // [60,68)
  unsigned short* pproj  = (unsigned short*)(W + 29360128);      // [28,36) kqv dead
  unsigned short* pdown  = (unsigned short*)(W + 46137344);      // [44,60) Qg..hv dead

  // weight conversion fp32 -> bf16 (single launch; outputs contiguous)
  f2b4_kernel<<<3145728 / 256, 256, 0, stream>>>(w_kqv, w_o, w_up, w_dn, wkqv_b);

  // 1. h = LN1(x)
  ln_kernel<<<TT, 256, 0, stream>>>(x, ln1_w, ln1_b, h_b);
  // 2. kqv = h @ w_kqv^T + b_kqv   (bf16 out)
  gemm3<0, 1, 0, 0><<<dim3(3 * DD / 128, TT / 128, 1), 256, 0, stream>>>(
      h_b, wkqv_b, b_kqv, nullptr, kqz, TT, 3 * DD, DD, DD);
  // 3. gather heads (Q pre-scaled) + V transpose
  gather_qkv<<<(NH * TT * DHD) / 256, 256, 0, stream>>>(kqz, Qg, Kg);
  transpose_v<<<dim3(TT / 64, NH), 256, 0, stream>>>(kqz, Vtg);
  // 4. attention -> hv bf16
  attn_mfma<<<dim3(TT / 64, NH), 256, 0, stream>>>(Qg, Kg, Vtg, hv_b);
  // 5a. proj split-K=2: bf16 partials (kqv region is dead)
  gemm3<0, 0, 0, 1><<<dim3(DD / 128, TT / 128, 2), 256, 0, stream>>>(
      hv_b, wo_b, nullptr, nullptr, pproj, TT, DD, DD, DD / 2);
  // 5b. x2 = x + b_o + p0 + p1
  reduce_k<2><<<TT * DD / 4 / 256, 256, 0, stream>>>(pproj, b_o, x, x2);
  // 6. h2 = LN2(x2)
  ln_kernel<<<TT, 256, 0, stream>>>(x2, ln2_w, ln2_b, h_b);
  // 7. z1 = gelu(h2 @ w_up^T + b_up)  (bf16 out)
  gemm3<1, 1, 0, 0><<<dim3(DFF / 128, TT / 128, 1), 256, 0, stream>>>(
      h_b, wup_b, b_up, nullptr, kqz, TT, DFF, DD, DD);
  // 8a. down-proj split-K=4: bf16 partials (Qg..hv region is dead)
  gemm3<0, 0, 0, 1><<<dim3(DD / 128, TT / 128, 4), 256, 0, stream>>>(
      kqz, wdn_b, nullptr, nullptr, pdown, TT, DD, DFF, DFF / 4);
  // 8b. out = x2 + b_dn + p0..p3
  reduce_k<4><<<TT * DD / 4 / 256, 256, 0, stream>>>(pdown, b_dn, x2, out);
}

// Round 6
// 171.442 us; speedup vs baseline: 1.0755x; 1.0755x over previous
//
#include <hip/hip_runtime.h>
#include <math.h>

#define TT 2048
#define DD 1024
#define NH 16
#define DHD 64
#define DFF 4096

typedef __attribute__((ext_vector_type(8))) short short8;
typedef __attribute__((ext_vector_type(4))) float f32x4;

#define MFMA16(a, b, c) __builtin_amdgcn_mfma_f32_16x16x32_bf16(a, b, c, 0, 0, 0)
#define GLDS16(gp, lp) __builtin_amdgcn_global_load_lds( \
    (const __attribute__((address_space(1))) void*)(gp), \
    (__attribute__((address_space(3))) void*)(lp), 16, 0, 0)

static __device__ __forceinline__ unsigned short f2b(float f) {
  unsigned u = __builtin_bit_cast(unsigned, f);
  u = u + 0x7fffu + ((u >> 16) & 1u);
  return (unsigned short)(u >> 16);
}
static __device__ __forceinline__ float b2f(unsigned short b) {
  return __builtin_bit_cast(float, (unsigned)b << 16);
}

// ---------------- fp32 -> bf16 convert: all 4 weight mats, one launch -------
__global__ __launch_bounds__(256) void f2b4_kernel(const float* __restrict__ s0,
    const float* __restrict__ s1, const float* __restrict__ s2,
    const float* __restrict__ s3, unsigned short* __restrict__ out) {
  int i = blockIdx.x * 256 + threadIdx.x;
  const float* s; int off;
  if (i < 786432)       { s = s0; off = 0; }
  else if (i < 1048576) { s = s1; off = 786432; }
  else if (i < 2097152) { s = s2; off = 1048576; }
  else                  { s = s3; off = 2097152; }
  float4 v = ((const float4*)s)[i - off];
  ushort4 o;
  o.x = f2b(v.x); o.y = f2b(v.y); o.z = f2b(v.z); o.w = f2b(v.w);
  ((ushort4*)out)[i] = o;
}

// ---------------- LayerNorm (fp32 in, bf16 out) ----------------
__global__ __launch_bounds__(256) void ln_kernel(const float* __restrict__ x,
    const float* __restrict__ w, const float* __restrict__ b,
    unsigned short* __restrict__ out) {
  int row = blockIdx.x;
  const float4* xr = (const float4*)(x + (size_t)row * DD);
  float4 v = xr[threadIdx.x];
  float s  = v.x + v.y + v.z + v.w;
  float ss = v.x * v.x + v.y * v.y + v.z * v.z + v.w * v.w;
  for (int o = 32; o > 0; o >>= 1) {
    s  += __shfl_down(s, o);
    ss += __shfl_down(ss, o);
  }
  __shared__ float red[10];
  int lane = threadIdx.x & 63, wv = threadIdx.x >> 6;
  if (lane == 0) { red[wv] = s; red[4 + wv] = ss; }
  __syncthreads();
  if (threadIdx.x == 0) {
    float S  = red[0] + red[1] + red[2] + red[3];
    float SS = red[4] + red[5] + red[6] + red[7];
    float mu  = S * (1.0f / DD);
    float var = SS * (1.0f / DD) - mu * mu;
    red[8] = mu;
    red[9] = rsqrtf(var + 1e-5f);
  }
  __syncthreads();
  float mu = red[8], inv = red[9];
  float4 wv4 = ((const float4*)w)[threadIdx.x];
  float4 bv4 = ((const float4*)b)[threadIdx.x];
  ushort4 o4;
  o4.x = f2b((v.x - mu) * inv * wv4.x + bv4.x);
  o4.y = f2b((v.y - mu) * inv * wv4.y + bv4.y);
  o4.z = f2b((v.z - mu) * inv * wv4.z + bv4.z);
  o4.w = f2b((v.w - mu) * inv * wv4.w + bv4.w);
  ((ushort4*)(out + (size_t)row * DD))[threadIdx.x] = o4;
}

// ---------------- bf16 MFMA GEMM v4: BK=64, 2-buf, counted vmcnt, XCD chunk -
// C[M,N] = A[M,K] * B[N,K]^T (+bias/gelu/resid) or bf16 partial (split-K).
// 128x128 tile, 256 threads (4 waves 2x2). LDS: 2 bufs x (A 16KB | B 16KB).
// Per wave per tile: 8 global_load_lds -> vmcnt counts exact (steady: 8).
// Block remap: XCD xcd=bid%8 owns a CX x CY chunk of (x, y+GYM*z) tile space
// so its resident blocks' A/B panels fit the 4MB per-XCD L2.
template<int FUSE_GELU, int OUT_BF16, int HAS_RESID, int PARTIAL>
__global__ __launch_bounds__(256) void gemm4(
    const unsigned short* __restrict__ A,   // [M,K] bf16
    const unsigned short* __restrict__ Bw,  // [N,K] bf16
    const float* __restrict__ bias,         // [N]
    const float* __restrict__ resid,        // [M,N] fp32
    void* __restrict__ Cout,
    int M, int N, int K, int KS, int CX, int CY) {
  __shared__ char lds[65536];
  const int tid = threadIdx.x;
  const int w = tid >> 6, l = tid & 63;
  const int l15 = l & 15, lhi = l >> 4;

  // chunked XCD remap (grid is 1D, = 8*CX*CY blocks)
  const int GX = N >> 7, GYM = M >> 7;
  const int xcd = blockIdx.x & 7, s = blockIdx.x >> 3;
  const int ncx = GX / CX;
  const int bx = (xcd % ncx) * CX + (s % CX);
  const int yz = (xcd / ncx) * CY + (s / CX);
  const int by = yz % GYM, bz = yz / GYM;

  const int row0 = by << 7, col0 = bx << 7;
  const int kbeg = bz * KS;
  const int wm = (w >> 1) * 64, wn = (w & 1) * 64;

  f32x4 acc[4][4] = {};

  // staging: LDS row (128B) == matrix row (64 bf16); XOR-swizzle byte col by
  // (row&7)<<4 via pre-swizzled global source (linear LDS dest).
  const int lr = l >> 3;                          // 0..7 == row&7 for all issues
  const int cb = ((l & 7) * 16) ^ (lr << 4);
  const char* aS = (const char*)A + ((size_t)(row0 + w * 32 + lr) * K + kbeg) * 2 + cb;
  const char* bS = (const char*)Bw + ((size_t)(col0 + w * 32 + lr) * K + kbeg) * 2 + cb;
  const size_t r8 = (size_t)K * 16;               // 8 matrix rows in bytes
  const int aO = w * 4096, bO = 16384 + w * 4096;
  const int NT = KS >> 6;                         // BK = 64

  auto STAGE = [&](int t) {
    char* base = lds + (t & 1) * 32768;
    const char* a = aS + (size_t)t * 128;
    const char* b = bS + (size_t)t * 128;
    GLDS16(a,            base + aO);
    GLDS16(a +     r8,   base + aO + 1024);
    GLDS16(a + 2 * r8,   base + aO + 2048);
    GLDS16(a + 3 * r8,   base + aO + 3072);
    GLDS16(b,            base + bO);
    GLDS16(b +     r8,   base + bO + 1024);
    GLDS16(b + 2 * r8,   base + bO + 2048);
    GLDS16(b + 3 * r8,   base + bO + 3072);
  };
  auto COMPUTE = [&](int t) {
    const char* Ab = lds + (t & 1) * 32768;
    const char* Bb = Ab + 16384;
    const int sw = (l15 & 7) << 4;
#pragma unroll
    for (int kk = 0; kk < 2; ++kk) {
      short8 af[4], bf[4];
#pragma unroll
      for (int mi = 0; mi < 4; ++mi)
        af[mi] = *(const short8*)(Ab + (wm + mi * 16 + l15) * 128 + ((kk * 64 + lhi * 16) ^ sw));
#pragma unroll
      for (int ni = 0; ni < 4; ++ni)
        bf[ni] = *(const short8*)(Bb + (wn + ni * 16 + l15) * 128 + ((kk * 64 + lhi * 16) ^ sw));
#pragma unroll
      for (int mi = 0; mi < 4; ++mi)
#pragma unroll
        for (int ni = 0; ni < 4; ++ni)
          acc[mi][ni] = MFMA16(af[mi], bf[ni], acc[mi][ni]);
    }
  };

  STAGE(0);
  for (int t = 0; t < NT; ++t) {
    if (t + 1 < NT) STAGE(t + 1);                 // prefetch stays in flight
    __builtin_amdgcn_sched_barrier(0);
    if (t + 1 < NT) asm volatile("s_waitcnt vmcnt(8)" ::: "memory");  // tile t done
    else            asm volatile("s_waitcnt vmcnt(0)" ::: "memory");
    __builtin_amdgcn_s_barrier();                 // all waves' tile-t loads done
    __builtin_amdgcn_sched_barrier(0);
    COMPUTE(t);
    __builtin_amdgcn_sched_barrier(0);
    __builtin_amdgcn_s_barrier();                 // reads done before overwrite
  }

  if (PARTIAL) {   // bf16 partials, no bias
    unsigned short* Cp = (unsigned short*)Cout + (size_t)bz * M * N;
#pragma unroll
    for (int mi = 0; mi < 4; ++mi)
#pragma unroll
      for (int r = 0; r < 4; ++r) {
        size_t row = (size_t)(row0 + wm + mi * 16 + lhi * 4 + r);
#pragma unroll
        for (int ni = 0; ni < 4; ++ni)
          Cp[row * N + col0 + wn + ni * 16 + l15] = f2b(acc[mi][ni][r]);
      }
    return;
  }

#pragma unroll
  for (int mi = 0; mi < 4; ++mi) {
#pragma unroll
    for (int r = 0; r < 4; ++r) {
      size_t row = (size_t)(row0 + wm + mi * 16 + lhi * 4 + r);
#pragma unroll
      for (int ni = 0; ni < 4; ++ni) {
        int col = col0 + wn + ni * 16 + l15;
        float v = acc[mi][ni][r] + bias[col];
        if (FUSE_GELU) {
          float u = v;
          v = 0.5f * u * (1.0f + tanhf(0.7978845608028654f * (u + 0.044715f * u * u * u)));
        }
        if (HAS_RESID) v += resid[row * N + col];
        if (OUT_BF16) ((unsigned short*)Cout)[row * N + col] = f2b(v);
        else          ((float*)Cout)[row * N + col] = v;
      }
    }
  }
}

// ---------------- split-K reduce: out = sum(bf16 partials) + bias + resid ---
template<int NP>
__global__ __launch_bounds__(256) void reduce_k(const unsigned short* __restrict__ p,
    const float* __restrict__ bias, const float* __restrict__ resid,
    float* __restrict__ out) {
  int i = blockIdx.x * 256 + threadIdx.x;      // over T*D/4
  float4 r = ((const float4*)resid)[i];
  float4 bb = ((const float4*)bias)[i & (DD / 4 - 1)];
  float o0 = r.x + bb.x, o1 = r.y + bb.y, o2 = r.z + bb.z, o3 = r.w + bb.w;
#pragma unroll
  for (int z = 0; z < NP; ++z) {
    ushort4 pv = ((const ushort4*)(p + (size_t)z * TT * DD))[i];
    o0 += b2f(pv.x); o1 += b2f(pv.y); o2 += b2f(pv.z); o3 += b2f(pv.w);
  }
  float4 o; o.x = o0; o.y = o1; o.z = o2; o.w = o3;
  ((float4*)out)[i] = o;
}

// ---------------- gather heads: kqv[T,3D] bf16 -> K/Q [H,T,DH] bf16 ---------
__global__ __launch_bounds__(256) void gather_qkv(const unsigned short* __restrict__ kqv,
    unsigned short* __restrict__ Q, unsigned short* __restrict__ K) {
  int idx = blockIdx.x * 256 + threadIdx.x;   // over H*T*DH
  int d = idx & 63;
  int t = (idx >> 6) & (TT - 1);
  int h = idx >> 17;
  int col = d * NH + h;
  const unsigned short* rowp = kqv + (size_t)t * (3 * DD);
  K[idx] = rowp[col];
  Q[idx] = f2b(b2f(rowp[DD + col]) * 8.0f);   // * sqrt(DH), exact in bf16
}

// ---------------- V transpose: kqv v-section -> Vt[H][DH][T] ----------------
__global__ __launch_bounds__(256) void transpose_v(const unsigned short* __restrict__ kqv,
    unsigned short* __restrict__ Vt) {
  const int h = blockIdx.y;
  const int t0 = blockIdx.x * 64;
  __shared__ unsigned short Vs[64][65];
  for (int idx = threadIdx.x; idx < 4096; idx += 256) {
    int t = idx >> 6, d = idx & 63;
    Vs[t][d] = kqv[(size_t)(t0 + t) * (3 * DD) + 2 * DD + d * NH + h];
  }
  __syncthreads();
  for (int idx = threadIdx.x; idx < 4096; idx += 256) {
    int d = idx >> 6, t = idx & 63;
    Vt[(size_t)(h * DHD + d) * TT + t0 + t] = Vs[t][d];
  }
}

// ---------------- MFMA flash attention: XCD chunk (2 heads/XCD), counted vmcnt
__global__ __launch_bounds__(256) void attn_mfma(
    const unsigned short* __restrict__ Q,   // [H,T,DH] bf16, pre-scaled
    const unsigned short* __restrict__ K,   // [H,T,DH]
    const unsigned short* __restrict__ Vt,  // [H,DH,T]
    unsigned short* __restrict__ hv) {      // [T,D] bf16, head-slow cols
  // remap: xcd = bid%8 owns heads {2*xcd, 2*xcd+1}, all 32 q-blocks each
  const int bid = blockIdx.x;
  const int xcd = bid & 7, s = bid >> 3;
  const int qb = 31 - (s & 31);              // heavy q-blocks first
  const int h  = xcd * 2 + (s >> 5);
  const int q0 = qb * 64;
  const int tid = threadIdx.x;
  const int w = tid >> 6, l = tid & 63;
  const int l15 = l & 15, lhi = l >> 4;

  __shared__ char lds[40960];   // 2 x (K 8KB | V 8KB) + Ps 8KB (per-wave 2KB)
  char* Ps = lds + 32768 + w * 2048;

  const char* KhB = (const char*)(K + (size_t)h * TT * DHD);
  const char* VhB = (const char*)(Vt + (size_t)h * DHD * TT);

  const unsigned short* Qbase = Q + ((size_t)h * TT + q0 + w * 16 + l15) * DHD;
  short8 qf0 = *(const short8*)(Qbase + lhi * 8);
  short8 qf1 = *(const short8*)(Qbase + 32 + lhi * 8);

  f32x4 oacc[4] = {};
  float m = -1e30f, lsum = 0.0f;

  const int lr = l >> 3;
  const int colb = ((l & 7) * 16) ^ (lr << 4);
  const int srow = w * 16 + lr;
  const int swz = (l15 & 7) << 4;

  auto stage = [&](int k0n, char* buf) {   // 4 GLDS per wave
    const char* ks = KhB + (size_t)(k0n + srow) * 128 + colb;
    GLDS16(ks, buf + w * 2048);
    GLDS16(ks + 8 * 128, buf + w * 2048 + 1024);
    const char* vs = VhB + (size_t)srow * (TT * 2) + (size_t)k0n * 2 + colb;
    GLDS16(vs, buf + 8192 + w * 2048);
    GLDS16(vs + 8 * (TT * 2), buf + 8192 + w * 2048 + 1024);
  };

  stage(0, lds);
  int cur = 0;

  for (int kt = 0; kt <= qb; ++kt) {
    if (kt < qb) stage((kt + 1) * 64, lds + (cur ^ 1) * 16384);
    __builtin_amdgcn_sched_barrier(0);
    if (kt < qb) asm volatile("s_waitcnt vmcnt(4)" ::: "memory");  // tile kt done
    else         asm volatile("s_waitcnt vmcnt(0)" ::: "memory");
    __builtin_amdgcn_s_barrier();
    __builtin_amdgcn_sched_barrier(0);

    const char* Kb = lds + cur * 16384;
    const char* Vb = Kb + 8192;

    // ---- S^T = K Q^T : sacc[nt][r] = S[key=nt*16+lhi*4+r][q=l15] ----
    f32x4 sacc[4] = {};
    __builtin_amdgcn_s_setprio(1);
#pragma unroll
    for (int nt = 0; nt < 4; ++nt) {
      const char* rp = Kb + (nt * 16 + l15) * 128;
      short8 kb0 = *(const short8*)(rp + ((lhi * 16) ^ swz));
      short8 kb1 = *(const short8*)(rp + ((64 + lhi * 16) ^ swz));
      sacc[nt] = MFMA16(kb0, qf0, sacc[nt]);
      sacc[nt] = MFMA16(kb1, qf1, sacc[nt]);
    }
    __builtin_amdgcn_s_setprio(0);

    if (kt == qb) {          // causal mask on diagonal tile (k0 == q0)
      const int qloc = w * 16 + l15;
#pragma unroll
      for (int nt = 0; nt < 4; ++nt)
#pragma unroll
        for (int r = 0; r < 4; ++r)
          if (nt * 16 + lhi * 4 + r > qloc) sacc[nt][r] = -1e30f;
    }

    // ---- online softmax (q = l15 per lane; reduce regs + lhi via shfl) ----
    float tmax = -1e30f;
#pragma unroll
    for (int nt = 0; nt < 4; ++nt)
#pragma unroll
      for (int r = 0; r < 4; ++r) tmax = fmaxf(tmax, sacc[nt][r]);
    tmax = fmaxf(tmax, __shfl_xor(tmax, 16));
    tmax = fmaxf(tmax, __shfl_xor(tmax, 32));
    float mnew = fmaxf(m, tmax);
    float al = __expf(m - mnew);
    m = mnew;
    float ssum = 0.0f;
#pragma unroll
    for (int nt = 0; nt < 4; ++nt)
#pragma unroll
      for (int r = 0; r < 4; ++r) {
        float p = __expf(sacc[nt][r] - mnew);
        sacc[nt][r] = p;
        ssum += p;
      }
    ssum += __shfl_xor(ssum, 16);
    ssum += __shfl_xor(ssum, 32);
    lsum = lsum * al + ssum;

    // ---- P -> per-wave LDS rows q=l15 (4 x ds_write_b64, swizzled) ----
    {
      char* pp = Ps + l15 * 128;
#pragma unroll
      for (int nt = 0; nt < 4; ++nt) {
        uint2 pk;
        pk.x = (unsigned)f2b(sacc[nt][0]) | ((unsigned)f2b(sacc[nt][1]) << 16);
        pk.y = (unsigned)f2b(sacc[nt][2]) | ((unsigned)f2b(sacc[nt][3]) << 16);
        *(uint2*)(pp + (((nt * 16 + lhi * 4) * 2) ^ swz)) = pk;
      }
    }

    // ---- rescale O (rows q = lhi*4+r; fetch al of that q) ----
    float alr[4];
#pragma unroll
    for (int r = 0; r < 4; ++r) alr[r] = __shfl(al, (l & 48) | (lhi * 4 + r));
#pragma unroll
    for (int dt = 0; dt < 4; ++dt)
#pragma unroll
      for (int r = 0; r < 4; ++r) oacc[dt][r] *= alr[r];

    // ---- O += P V ----
    const char* pr = Ps + l15 * 128;
    short8 pa0 = *(const short8*)(pr + ((lhi * 16) ^ swz));
    short8 pa1 = *(const short8*)(pr + ((64 + lhi * 16) ^ swz));
    __builtin_amdgcn_s_setprio(1);
#pragma unroll
    for (int dt = 0; dt < 4; ++dt) {
      const char* vr = Vb + (dt * 16 + l15) * 128;
      short8 vb0 = *(const short8*)(vr + ((lhi * 16) ^ swz));
      short8 vb1 = *(const short8*)(vr + ((64 + lhi * 16) ^ swz));
      oacc[dt] = MFMA16(pa0, vb0, oacc[dt]);
      oacc[dt] = MFMA16(pa1, vb1, oacc[dt]);
    }
    __builtin_amdgcn_s_setprio(0);

    __builtin_amdgcn_sched_barrier(0);
    __builtin_amdgcn_s_barrier();            // raw: prefetch stays in flight
    cur ^= 1;
  }

  float lr4[4];
#pragma unroll
  for (int r = 0; r < 4; ++r)
    lr4[r] = 1.0f / __shfl(lsum, (l & 48) | (lhi * 4 + r));
#pragma unroll
  for (int r = 0; r < 4; ++r) {
    size_t orow = (size_t)(q0 + w * 16 + lhi * 4 + r) * DD + h * 64;
#pragma unroll
    for (int dt = 0; dt < 4; ++dt)
      hv[orow + dt * 16 + l15] = f2b(oacc[dt][r] * lr4[r]);
  }
}

// ---------------- launch ----------------
extern "C" void kernel_launch(void* const* d_in, const int* in_sizes, int n_in,
                              void* d_out, int out_size, void* d_ws, size_t ws_size,
                              hipStream_t stream) {
  const float* x     = (const float*)d_in[0];
  const float* w_kqv = (const float*)d_in[1];
  const float* b_kqv = (const float*)d_in[2];
  const float* w_o   = (const float*)d_in[3];
  const float* b_o   = (const float*)d_in[4];
  const float* ln1_w = (const float*)d_in[5];
  const float* ln1_b = (const float*)d_in[6];
  const float* ln2_w = (const float*)d_in[7];
  const float* ln2_b = (const float*)d_in[8];
  const float* w_up  = (const float*)d_in[9];
  const float* b_up  = (const float*)d_in[10];
  const float* w_dn  = (const float*)d_in[11];
  const float* b_dn  = (const float*)d_in[12];
  float* out = (float*)d_out;

  char* W = (char*)d_ws;
  unsigned short* wkqv_b = (unsigned short*)(W);                 // [0,6) MiB
  unsigned short* wo_b   = (unsigned short*)(W + 6291456);       // [6,8)
  unsigned short* wup_b  = (unsigned short*)(W + 8388608);       // [8,16)
  unsigned short* wdn_b  = (unsigned short*)(W + 16777216);      // [16,24)
  unsigned short* h_b    = (unsigned short*)(W + 25165824);      // [24,28)
  unsigned short* kqz    = (unsigned short*)(W + 29360128);      // [28,44) kqv then z1
  unsigned short* Qg     = (unsigned short*)(W + 46137344);      // [44,48)
  unsigned short* Kg     = (unsigned short*)(W + 50331648);      // [48,52)
  unsigned short* Vtg    = (unsigned short*)(W + 54525952);      // [52,56)
  unsigned short* hv_b   = (unsigned short*)(W + 58720256);      // [56,60)
  float*          x2     = (float*)(W + 62914560);               // [60,68)
  unsigned short* pproj  = (unsigned short*)(W + 29360128);      // [28,36) kqv dead
  unsigned short* pdown  = (unsigned short*)(W + 46137344);      // [44,60) Qg..hv dead

  // weight conversion fp32 -> bf16 (single launch; outputs contiguous)
  f2b4_kernel<<<3145728 / 256, 256, 0, stream>>>(w_kqv, w_o, w_up, w_dn, wkqv_b);

  // 1. h = LN1(x)
  ln_kernel<<<TT, 256, 0, stream>>>(x, ln1_w, ln1_b, h_b);
  // 2. kqv = h @ w_kqv^T + b_kqv  (bf16 out); grid 384 = 8 * (6x8) chunks
  gemm4<0, 1, 0, 0><<<384, 256, 0, stream>>>(
      h_b, wkqv_b, b_kqv, nullptr, kqz, TT, 3 * DD, DD, DD, 6, 8);
  // 3. gather heads (Q pre-scaled) + V transpose
  gather_qkv<<<(NH * TT * DHD) / 256, 256, 0, stream>>>(kqz, Qg, Kg);
  transpose_v<<<dim3(TT / 64, NH), 256, 0, stream>>>(kqz, Vtg);
  // 4. attention -> hv bf16; grid 512, 2 heads per XCD
  attn_mfma<<<512, 256, 0, stream>>>(Qg, Kg, Vtg, hv_b);
  // 5a. proj split-K=2: bf16 partials; grid 256 = 8 * (8x4)
  gemm4<0, 0, 0, 1><<<256, 256, 0, stream>>>(
      hv_b, wo_b, nullptr, nullptr, pproj, TT, DD, DD, DD / 2, 8, 4);
  // 5b. x2 = x + b_o + p0 + p1
  reduce_k<2><<<TT * DD / 4 / 256, 256, 0, stream>>>(pproj, b_o, x, x2);
  // 6. h2 = LN2(x2)
  ln_kernel<<<TT, 256, 0, stream>>>(x2, ln2_w, ln2_b, h_b);
  // 7. z1 = gelu(h2 @ w_up^T + b_up)  (bf16 out); grid 512 = 8 * (8x8)
  gemm4<1, 1, 0, 0><<<512, 256, 0, stream>>>(
      h_b, wup_b, b_up, nullptr, kqz, TT, DFF, DD, DD, 8, 8);
  // 8a. down-proj split-K=4: bf16 partials; grid 512 = 8 * (8x8)
  gemm4<0, 0, 0, 1><<<512, 256, 0, stream>>>(
      kqz, wdn_b, nullptr, nullptr, pdown, TT, DD, DFF, DFF / 4, 8, 8);
  // 8b. out = x2 + b_dn + p0..p3
  reduce_k<4><<<TT * DD / 4 / 256, 256, 0, stream>>>(pdown, b_dn, x2, out);
}